// Round 12
// baseline (155.528 us; speedup 1.0000x reference)
//
#include <hip/hip_runtime.h>
#include <math.h>

#define NATOMS 122880
#define BATCH 4096
#define EPS 1e-3f

// Degree-block offsets (cumsum of COUNTS) and tile (32-atom) cumulative table.
__constant__ int d_OFFS[12] = {0,1024,25600,62464,99328,119808,121856,122368,122624,122752,122816,122880};
__constant__ int d_TCUM[12] = {0,32,800,1952,3104,3744,3808,3824,3832,3836,3838,3840};

struct Adj { const int* p[10]; };

typedef __attribute__((ext_vector_type(8))) short bf16x8;
typedef __attribute__((ext_vector_type(4))) float f32x4;

__device__ inline float bf2f(ushort u) { return __uint_as_float(((unsigned)u) << 16); }
__device__ inline ushort f2bf(float f) {
    unsigned u = __float_as_uint(f);
    return (ushort)((u + 0x7fffu + ((u >> 16) & 1u)) >> 16);   // RNE
}

// tanh(x) = 1 - 2/(exp2(x*2*log2e)+1); HW exp2+rcp, ~5 instrs, exact limits.
__device__ inline float fast_tanh(float x) {
    float e = __builtin_amdgcn_exp2f(x * 2.8853900817779268f);
    return 1.f - 2.f * __builtin_amdgcn_rcpf(e + 1.f);
}

// ---- merged pre-pass: cvt_x_pad | build_wt | hist (hist[] pre-zeroed by memset) ----
// blocks [0,3840): atoms f32 (Nx75) -> xb bf16 (Nx80, pad 0)
// blocks [3840,4664): build Wt1/Wt2/Wt3
// blocks [4664,5144): histogram of membership (atomicAdd into pre-zeroed hist)
__global__ __launch_bounds__(256)
void prep_kernel(const float* __restrict__ x, ushort* __restrict__ xb,
                 const float* __restrict__ W1, const float* __restrict__ W2,
                 const float* __restrict__ W3,
                 ushort* __restrict__ Wt1, ushort* __restrict__ Wt2,
                 ushort* __restrict__ Wt3,
                 const int* __restrict__ mem, int* __restrict__ hist)
{
    __shared__ float s_row[2400];           // 32 x 75 (only used by cvt branch)
    const int tid = threadIdx.x;
    const int bx  = blockIdx.x;
    if (bx < 3840) {
        const size_t base = (size_t)bx * 32;
        for (int e = tid; e < 2400; e += 256) s_row[e] = x[base * 75 + e];
        __syncthreads();
        for (int e = tid; e < 320; e += 256) {  // 32 rows x 10 chunks
            int a = e / 10, ch = e - a * 10;
            unsigned px[4];
            #pragma unroll
            for (int q = 0; q < 4; ++q) {
                int k0 = ch * 8 + q * 2, k1 = k0 + 1;
                float v0 = (k0 < 75) ? s_row[a * 75 + k0] : 0.f;
                float v1 = (k1 < 75) ? s_row[a * 75 + k1] : 0.f;
                px[q] = (unsigned)f2bf(v0) | ((unsigned)f2bf(v1) << 16);
            }
            uint4 pv; pv.x = px[0]; pv.y = px[1]; pv.z = px[2]; pv.w = px[3];
            *(uint4*)(xb + (base + a) * 80 + ch * 8) = pv;
        }
    } else if (bx < 4664) {
        int idx = (bx - 3840) * 256 + tid;      // < 210,944
        if (idx < 112640) {
            int m = idx / 10240;
            int rem = idx - m * 10240;
            int n = rem / 160, k = rem - n * 160;
            float v = 0.f;
            if (k < 80) {
                if (k < 75) v = (m == 0) ? 0.f : W1[(size_t)(2*m-2)*75*64 + k*64 + n];
            } else {
                int kk = k - 80;
                if (kk < 75) v = (m == 0) ? W1[(size_t)20*75*64 + kk*64 + n]
                                          : W1[(size_t)(2*m-1)*75*64 + kk*64 + n];
            }
            Wt1[(size_t)m*10240 + n*160 + k] = f2bf(v);
        } else if (idx < 202752) {
            int i2 = idx - 112640;
            int m = i2 / 8192;
            int rem = i2 - m * 8192;
            int n = rem / 128, k = rem - n * 128;
            float v;
            if (k < 64) v = (m == 0) ? 0.f : W2[(size_t)(2*m-2)*64*64 + k*64 + n];
            else        v = (m == 0) ? W2[(size_t)20*64*64 + (k-64)*64 + n]
                                     : W2[(size_t)(2*m-1)*64*64 + (k-64)*64 + n];
            Wt2[(size_t)m*8192 + n*128 + k] = f2bf(v);
        } else {
            int i3 = idx - 202752;                  // 8192: Wt3[n][k] = W3[k][n]
            int n = i3 >> 6, k = i3 & 63;
            Wt3[(size_t)n*64 + k] = f2bf(W3[(size_t)k*128 + n]);
        }
    } else {
        int i = (bx - 4664) * 256 + tid;            // 480 blocks -> NATOMS
        atomicAdd(&hist[mem[i]], 1);
    }
}

__global__ __launch_bounds__(1024)
void scan_kernel(const int* __restrict__ hist, int* __restrict__ cursor) {
    __shared__ int s_sums[16];
    const int t = threadIdx.x;
    const int lane = t & 63, wid = t >> 6;
    int4 v = ((const int4*)hist)[t];
    int tot = v.x + v.y + v.z + v.w;
    int x = tot;
    #pragma unroll
    for (int o = 1; o < 64; o <<= 1) { int y = __shfl_up(x, o); if (lane >= o) x += y; }
    if (lane == 63) s_sums[wid] = x;
    __syncthreads();
    if (wid == 0) {
        int y = (lane < 16) ? s_sums[lane] : 0;
        #pragma unroll
        for (int o = 1; o < 16; o <<= 1) { int z = __shfl_up(y, o); if (lane >= o) y += z; }
        if (lane < 16) s_sums[lane] = y;
    }
    __syncthreads();
    int base = (wid > 0 ? s_sums[wid - 1] : 0) + (x - tot);
    int4 c;
    c.x = base; c.y = base + v.x; c.z = base + v.x + v.y; c.w = base + v.x + v.y + v.z;
    ((int4*)cursor)[t] = c;
}

__global__ __launch_bounds__(256)
void scatter_kernel(const int* __restrict__ mem, int* __restrict__ cursor,
                    int* __restrict__ sidx) {
    int i = blockIdx.x * 256 + threadIdx.x;    // grid 480
    int m = mem[i];
    int p = atomicAdd(&cursor[m], 1);
    sidx[p] = i;
}

// ---------------- conv (MFMA) ----------------

template<int FP, int KPAD, int D>
__device__ inline void stage_rows_v2(ushort (*s_A)[KPAD], const int* __restrict__ s_adj,
                                     const ushort* __restrict__ xb, int row0, int tid)
{
    constexpr int NCH = FP / 8;
    for (int e = tid; e < 32 * NCH; e += 256) {
        const int a = e / NCH, ch = e - a * NCH;
        const int co = ch * 8;
        uint4 sv = *(const uint4*)(xb + (size_t)(row0 + a) * FP + co);
        float acc[8] = {0.f,0.f,0.f,0.f,0.f,0.f,0.f,0.f};
        #pragma unroll
        for (int j = 0; j < D; ++j) {
            uint4 nv = *(const uint4*)(xb + (size_t)s_adj[a * D + j] * FP + co);
            unsigned u[4] = {nv.x, nv.y, nv.z, nv.w};
            #pragma unroll
            for (int q = 0; q < 4; ++q) {
                acc[2*q]   += __uint_as_float(u[q] << 16);
                acc[2*q+1] += __uint_as_float(u[q] & 0xFFFF0000u);
            }
        }
        unsigned pz[4];
        #pragma unroll
        for (int q = 0; q < 4; ++q)
            pz[q] = (unsigned)f2bf(acc[2*q]) | ((unsigned)f2bf(acc[2*q+1]) << 16);
        uint4 rv; rv.x = pz[0]; rv.y = pz[1]; rv.z = pz[2]; rv.w = pz[3];
        *(uint4*)&s_A[a][co] = rv;
        *(uint4*)&s_A[a][FP + co] = sv;
    }
}

template<int FP, int KTOT, int KPAD>
__global__ __launch_bounds__(256)
void conv_mfma(const ushort* __restrict__ xb, const ushort* __restrict__ Wt,
               const float* __restrict__ b,
               const float* __restrict__ g, const float* __restrict__ beta,
               const float* __restrict__ mean, const float* __restrict__ var,
               Adj adj, ushort* __restrict__ out)
{
    __shared__ ushort s_A[32][KPAD];
    __shared__ int s_adj[320];

    const int tid = threadIdx.x;
    const int bx  = blockIdx.x;
    int d = 0;
    #pragma unroll
    for (int i = 1; i <= 10; ++i) if (bx >= d_TCUM[i]) d = i;
    const int tile = bx - d_TCUM[d];
    const int row0 = d_OFFS[d] + tile * 32;

    if (d > 0) {
        const int* ap = adj.p[d-1] + (size_t)tile * 32 * d;
        for (int e = tid; e < 32 * d; e += 256) s_adj[e] = ap[e];
    }
    __syncthreads();

    switch (d) {
        case 0:  stage_rows_v2<FP,KPAD,0 >(s_A, s_adj, xb, row0, tid); break;
        case 1:  stage_rows_v2<FP,KPAD,1 >(s_A, s_adj, xb, row0, tid); break;
        case 2:  stage_rows_v2<FP,KPAD,2 >(s_A, s_adj, xb, row0, tid); break;
        case 3:  stage_rows_v2<FP,KPAD,3 >(s_A, s_adj, xb, row0, tid); break;
        case 4:  stage_rows_v2<FP,KPAD,4 >(s_A, s_adj, xb, row0, tid); break;
        case 5:  stage_rows_v2<FP,KPAD,5 >(s_A, s_adj, xb, row0, tid); break;
        case 6:  stage_rows_v2<FP,KPAD,6 >(s_A, s_adj, xb, row0, tid); break;
        case 7:  stage_rows_v2<FP,KPAD,7 >(s_A, s_adj, xb, row0, tid); break;
        case 8:  stage_rows_v2<FP,KPAD,8 >(s_A, s_adj, xb, row0, tid); break;
        case 9:  stage_rows_v2<FP,KPAD,9 >(s_A, s_adj, xb, row0, tid); break;
        default: stage_rows_v2<FP,KPAD,10>(s_A, s_adj, xb, row0, tid); break;
    }
    __syncthreads();

    const int w = tid >> 6, lane = tid & 63;
    const int r = w & 1, c = w >> 1;
    const int l15 = lane & 15, lg = lane >> 4;
    const int kgrp = lg * 8;

    f32x4 acc0 = {}, acc1 = {};
    const ushort* ap0 = &s_A[r * 16 + l15][kgrp];
    const ushort* wt0 = Wt + ((size_t)d * 64 + c * 32 + l15) * KTOT + kgrp;
    const ushort* wt1 = wt0 + 16 * KTOT;
    #pragma unroll
    for (int ks = 0; ks < KTOT / 32; ++ks) {
        bf16x8 af = *(const bf16x8*)(ap0 + ks * 32);
        bf16x8 b0 = *(const bf16x8*)(wt0 + ks * 32);
        bf16x8 b1 = *(const bf16x8*)(wt1 + ks * 32);
        acc0 = __builtin_amdgcn_mfma_f32_16x16x32_bf16(af, b0, acc0, 0, 0, 0);
        acc1 = __builtin_amdgcn_mfma_f32_16x16x32_bf16(af, b1, acc1, 0, 0, 0);
    }

    const int col0 = c * 32 + l15;
    const int col1 = col0 + 16;
    float bias0, bias1;
    if (d > 0) {
        bias0 = b[(2*d-2)*64 + col0] + b[(2*d-1)*64 + col0];
        bias1 = b[(2*d-2)*64 + col1] + b[(2*d-1)*64 + col1];
    } else {
        bias0 = b[20*64 + col0];
        bias1 = b[20*64 + col1];
    }
    const float g0 = g[col0], be0 = beta[col0], m0 = mean[col0], r0 = rsqrtf(var[col0] + EPS);
    const float g1 = g[col1], be1 = beta[col1], m1 = mean[col1], r1 = rsqrtf(var[col1] + EPS);
    const int rbase = row0 + r * 16 + lg * 4;
    #pragma unroll
    for (int i = 0; i < 4; ++i) {
        float t0 = fast_tanh(acc0[i] + bias0);
        float t1 = fast_tanh(acc1[i] + bias1);
        out[(size_t)(rbase + i) * 64 + col0] = f2bf(g0 * (t0 - m0) * r0 + be0);
        out[(size_t)(rbase + i) * 64 + col1] = f2bf(g1 * (t1 - m1) * r1 + be1);
    }
}

// ---------------- pool (bf16, vectorized 16B/lane) ----------------

template<int D>
__device__ inline void pool_body(const ushort* __restrict__ h, ushort* __restrict__ out,
                                 const int* __restrict__ s_adj, int row0, int tid)
{
    const int a = tid >> 3, co = (tid & 7) * 8;   // 32 atoms x 8 chunks
    uint4 sv = *(const uint4*)(h + (size_t)(row0 + a) * 64 + co);
    unsigned su[4] = {sv.x, sv.y, sv.z, sv.w};
    float mx[8];
    #pragma unroll
    for (int q = 0; q < 4; ++q) {
        mx[2*q]   = __uint_as_float(su[q] << 16);
        mx[2*q+1] = __uint_as_float(su[q] & 0xFFFF0000u);
    }
    #pragma unroll
    for (int j = 0; j < D; ++j) {
        uint4 nv = *(const uint4*)(h + (size_t)s_adj[a * D + j] * 64 + co);
        unsigned u[4] = {nv.x, nv.y, nv.z, nv.w};
        #pragma unroll
        for (int q = 0; q < 4; ++q) {
            mx[2*q]   = fmaxf(mx[2*q],   __uint_as_float(u[q] << 16));
            mx[2*q+1] = fmaxf(mx[2*q+1], __uint_as_float(u[q] & 0xFFFF0000u));
        }
    }
    unsigned pz[4];
    #pragma unroll
    for (int q = 0; q < 4; ++q)   // exact: all values are bf16-representable
        pz[q] = (__float_as_uint(mx[2*q]) >> 16) | (__float_as_uint(mx[2*q+1]) & 0xFFFF0000u);
    uint4 pv; pv.x = pz[0]; pv.y = pz[1]; pv.z = pz[2]; pv.w = pz[3];
    *(uint4*)(out + (size_t)(row0 + a) * 64 + co) = pv;
}

__global__ __launch_bounds__(256)
void pool_tile(const ushort* __restrict__ h, ushort* __restrict__ out, Adj adj)
{
    __shared__ int s_adj[320];
    const int tid = threadIdx.x;
    const int bx  = blockIdx.x;
    int d = 0;
    #pragma unroll
    for (int i = 1; i <= 10; ++i) if (bx >= d_TCUM[i]) d = i;
    const int tile = bx - d_TCUM[d];
    const int row0 = d_OFFS[d] + tile * 32;

    if (d > 0) {
        const int* ap = adj.p[d-1] + (size_t)tile * 32 * d;
        for (int e = tid; e < 32 * d; e += 256) s_adj[e] = ap[e];
        __syncthreads();
    }
    switch (d) {
        case 0:  pool_body<0 >(h, out, s_adj, row0, tid); break;
        case 1:  pool_body<1 >(h, out, s_adj, row0, tid); break;
        case 2:  pool_body<2 >(h, out, s_adj, row0, tid); break;
        case 3:  pool_body<3 >(h, out, s_adj, row0, tid); break;
        case 4:  pool_body<4 >(h, out, s_adj, row0, tid); break;
        case 5:  pool_body<5 >(h, out, s_adj, row0, tid); break;
        case 6:  pool_body<6 >(h, out, s_adj, row0, tid); break;
        case 7:  pool_body<7 >(h, out, s_adj, row0, tid); break;
        case 8:  pool_body<8 >(h, out, s_adj, row0, tid); break;
        case 9:  pool_body<9 >(h, out, s_adj, row0, tid); break;
        default: pool_body<10>(h, out, s_adj, row0, tid); break;
    }
}

// -- dense d1 (MFMA, A-fragments direct from global) + per-molecule reduce + fused final --
__global__ __launch_bounds__(256)
void dense_seg_direct(const ushort* __restrict__ h, const ushort* __restrict__ Wt3,
                      const float* __restrict__ b,
                      const float* __restrict__ g3, const float* __restrict__ b3,
                      const float* __restrict__ m3, const float* __restrict__ v3,
                      const int* __restrict__ sidx,
                      const int* __restrict__ hist, const int* __restrict__ endc,
                      const float* __restrict__ x_add,
                      const float* __restrict__ d2W, const float* __restrict__ d2b,
                      const float* __restrict__ d3W, const float* __restrict__ d3b,
                      float* __restrict__ out)
{
    __shared__ float s_sum[4][64];
    __shared__ float s_max[4][64];
    __shared__ float s_red[4];

    const int mol = blockIdx.x;
    const int cnt = hist[mol];
    const int start = endc[mol] - cnt;

    const int tid = threadIdx.x;
    const int w = tid >> 6, lane = tid & 63;
    const int r = w & 1, cb = (w >> 1) * 64;
    const int l15 = lane & 15, lg = lane >> 4;

    int   col[4];
    float bias[4], gg[4], bb[4], mm[4], rr[4];
    #pragma unroll
    for (int j = 0; j < 4; ++j) {
        col[j]  = cb + j * 16 + l15;
        bias[j] = b[col[j]];
        gg[j] = g3[col[j]]; bb[j] = b3[col[j]]; mm[j] = m3[col[j]];
        rr[j] = rsqrtf(v3[col[j]] + EPS);
    }

    const float NEGINF = __int_as_float(0xFF800000);
    float rsum[4] = {0.f, 0.f, 0.f, 0.f};
    float rmax[4] = {NEGINF, NEGINF, NEGINF, NEGINF};

    for (int base = 0; base < cnt; base += 32) {
        int gidx = start + base + r * 16 + l15;
        int gmax = NATOMS - 1;
        gidx = gidx < gmax ? gidx : gmax;
        int row = sidx[gidx];
        const ushort* hp = h + (size_t)row * 64 + lg * 8;
        bf16x8 af0 = *(const bf16x8*)(hp);
        bf16x8 af1 = *(const bf16x8*)(hp + 32);

        f32x4 acc[4] = {};
        #pragma unroll
        for (int j = 0; j < 4; ++j) {
            const ushort* wt = Wt3 + (size_t)col[j] * 64 + lg * 8;
            bf16x8 bv0 = *(const bf16x8*)(wt);
            bf16x8 bv1 = *(const bf16x8*)(wt + 32);
            acc[j] = __builtin_amdgcn_mfma_f32_16x16x32_bf16(af0, bv0, acc[j], 0, 0, 0);
            acc[j] = __builtin_amdgcn_mfma_f32_16x16x32_bf16(af1, bv1, acc[j], 0, 0, 0);
        }

        const int rowbase = base + r * 16 + lg * 4;
        #pragma unroll
        for (int i = 0; i < 4; ++i) {
            if (rowbase + i < cnt) {
                #pragma unroll
                for (int j = 0; j < 4; ++j) {
                    float hv = gg[j] * (fast_tanh(acc[j][i] + bias[j]) - mm[j]) * rr[j] + bb[j];
                    rsum[j] += hv;
                    rmax[j] = fmaxf(rmax[j], hv);
                }
            }
        }
    }

    #pragma unroll
    for (int j = 0; j < 4; ++j) {
        rsum[j] += __shfl_xor(rsum[j], 16);
        rsum[j] += __shfl_xor(rsum[j], 32);
        rmax[j] = fmaxf(rmax[j], __shfl_xor(rmax[j], 16));
        rmax[j] = fmaxf(rmax[j], __shfl_xor(rmax[j], 32));
    }
    if (lane < 16) {
        #pragma unroll
        for (int j = 0; j < 4; ++j) {
            s_sum[w][j * 16 + lane] = rsum[j];
            s_max[w][j * 16 + lane] = rmax[j];
        }
    }
    __syncthreads();

    {
        const int part2 = tid >> 7;          // 0 = sum half, 1 = max half
        const int c  = tid & 127;
        const int ch = c >> 6, cc = c & 63;
        float val;
        if (part2 == 0) val = s_sum[2*ch][cc] + s_sum[2*ch + 1][cc];
        else            val = fmaxf(s_max[2*ch][cc], s_max[2*ch + 1][cc]);
        float p = fast_tanh(val) * d2W[part2 * 128 + c];
        #pragma unroll
        for (int o = 32; o > 0; o >>= 1) p += __shfl_down(p, o);
        if (lane == 0) s_red[w] = p;
    }
    __syncthreads();
    if (tid == 0) {
        float mv = s_red[0] + s_red[1] + s_red[2] + s_red[3] + d2b[0];
        float rv = mv * d3W[0] + d3b[0];
        for (int i = 0; i < 15; ++i) rv += x_add[(size_t)mol * 15 + i] * d3W[1 + i];
        out[mol] = rv;
    }
}

extern "C" void kernel_launch(void* const* d_in, const int* in_sizes, int n_in,
                              void* d_out, int out_size, void* d_ws, size_t ws_size,
                              hipStream_t stream) {
    const float* atoms      = (const float*)d_in[0];
    const int*   membership = (const int*)  d_in[1];
    Adj adj;
    for (int i = 0; i < 10; ++i) adj.p[i] = (const int*)d_in[2 + i];
    const float* x_add = (const float*)d_in[12];
    const float* gc1_W = (const float*)d_in[13];
    const float* gc1_b = (const float*)d_in[14];
    const float* gc2_W = (const float*)d_in[15];
    const float* gc2_b = (const float*)d_in[16];
    const float* bn1_g = (const float*)d_in[17];
    const float* bn1_b = (const float*)d_in[18];
    const float* bn1_m = (const float*)d_in[19];
    const float* bn1_v = (const float*)d_in[20];
    const float* bn3_g = (const float*)d_in[21];
    const float* bn3_b = (const float*)d_in[22];
    const float* bn3_m = (const float*)d_in[23];
    const float* bn3_v = (const float*)d_in[24];
    const float* d1_W  = (const float*)d_in[25];
    const float* d1_b  = (const float*)d_in[26];
    const float* d2_W  = (const float*)d_in[27];
    const float* d2_b  = (const float*)d_in[28];
    const float* d3_W  = (const float*)d_in[29];
    const float* d3_b  = (const float*)d_in[30];
    float* out = (float*)d_out;

    // ---- workspace layout (elements) ----
    ushort* xb  = (ushort*)d_ws;                       // 122880*80 = 9,830,400
    ushort* hA  = xb  + (size_t)9830400;               // 7,864,320
    ushort* hB  = hA  + (size_t)7864320;               // 7,864,320
    ushort* Wt1 = hB  + (size_t)7864320;               // 112,640
    ushort* Wt2 = Wt1 + (size_t)112640;                // 90,112
    ushort* Wt3 = Wt2 + (size_t)90112;                 // 8,192
    int*   sidx = (int*)(Wt3 + (size_t)8192);          // NATOMS
    int*   hist = sidx + NATOMS;                       // 4096
    int* cursor = hist + BATCH;                        // 4096

    // zero hist via DMA (graph-capturable), then merged pre-pass incl. histogram
    hipMemsetAsync(hist, 0, BATCH * sizeof(int), stream);
    prep_kernel<<<5144, 256, 0, stream>>>(atoms, xb, gc1_W, gc2_W, d1_W,
                                          Wt1, Wt2, Wt3, membership, hist);
    scan_kernel<<<1, 1024, 0, stream>>>(hist, cursor);
    scatter_kernel<<<480, 256, 0, stream>>>(membership, cursor, sidx);
    // after scatter, cursor[m] == end offset of molecule m

    // main pipeline
    conv_mfma<80,160,168><<<3840, 256, 0, stream>>>(xb, Wt1, gc1_b,
                                                    bn1_g, bn1_b, bn1_m, bn1_v, adj, hA);
    pool_tile<<<3840, 256, 0, stream>>>(hA, hB, adj);
    conv_mfma<64,128,136><<<3840, 256, 0, stream>>>(hB, Wt2, gc2_b,
                                                    bn1_g, bn1_b, bn1_m, bn1_v, adj, hA);
    pool_tile<<<3840, 256, 0, stream>>>(hA, hB, adj);
    dense_seg_direct<<<BATCH, 256, 0, stream>>>(hB, Wt3, d1_b,
                                                bn3_g, bn3_b, bn3_m, bn3_v,
                                                sidx, hist, cursor,
                                                x_add, d2_W, d2_b, d3_W, d3_b, out);
}

// Round 13
// 149.176 us; speedup vs baseline: 1.0426x; 1.0426x over previous
//
#include <hip/hip_runtime.h>
#include <math.h>

#define NATOMS 122880
#define BATCH 4096
#define EPS 1e-3f

// Degree-block offsets (cumsum of COUNTS) and tile (32-atom) cumulative table.
__constant__ int d_OFFS[12] = {0,1024,25600,62464,99328,119808,121856,122368,122624,122752,122816,122880};
__constant__ int d_TCUM[12] = {0,32,800,1952,3104,3744,3808,3824,3832,3836,3838,3840};

struct Adj { const int* p[10]; };

typedef __attribute__((ext_vector_type(8))) short bf16x8;
typedef __attribute__((ext_vector_type(4))) float f32x4;

__device__ inline float bf2f(ushort u) { return __uint_as_float(((unsigned)u) << 16); }
__device__ inline ushort f2bf(float f) {
    unsigned u = __float_as_uint(f);
    return (ushort)((u + 0x7fffu + ((u >> 16) & 1u)) >> 16);   // RNE
}

// tanh(x) = 1 - 2/(exp2(x*2*log2e)+1); HW exp2+rcp, ~5 instrs, exact limits.
__device__ inline float fast_tanh(float x) {
    float e = __builtin_amdgcn_exp2f(x * 2.8853900817779268f);
    return 1.f - 2.f * __builtin_amdgcn_rcpf(e + 1.f);
}

// ---- merged pre-pass: cvt_x_pad | build_wt | zero_hist ----
// blocks [0,3840): atoms f32 (Nx75) -> xb bf16 (Nx80, pad 0)
// blocks [3840,4664): build Wt1/Wt2/Wt3
// blocks [4664,4680): zero hist
__global__ __launch_bounds__(256)
void prep_kernel(const float* __restrict__ x, ushort* __restrict__ xb,
                 const float* __restrict__ W1, const float* __restrict__ W2,
                 const float* __restrict__ W3,
                 ushort* __restrict__ Wt1, ushort* __restrict__ Wt2,
                 ushort* __restrict__ Wt3, int* __restrict__ hist)
{
    __shared__ float s_row[2400];           // 32 x 75 (only used by cvt branch)
    const int tid = threadIdx.x;
    const int bx  = blockIdx.x;
    if (bx < 3840) {
        const size_t base = (size_t)bx * 32;
        for (int e = tid; e < 2400; e += 256) s_row[e] = x[base * 75 + e];
        __syncthreads();
        for (int e = tid; e < 320; e += 256) {  // 32 rows x 10 chunks
            int a = e / 10, ch = e - a * 10;
            unsigned px[4];
            #pragma unroll
            for (int q = 0; q < 4; ++q) {
                int k0 = ch * 8 + q * 2, k1 = k0 + 1;
                float v0 = (k0 < 75) ? s_row[a * 75 + k0] : 0.f;
                float v1 = (k1 < 75) ? s_row[a * 75 + k1] : 0.f;
                px[q] = (unsigned)f2bf(v0) | ((unsigned)f2bf(v1) << 16);
            }
            uint4 pv; pv.x = px[0]; pv.y = px[1]; pv.z = px[2]; pv.w = px[3];
            *(uint4*)(xb + (base + a) * 80 + ch * 8) = pv;
        }
    } else if (bx < 4664) {
        int idx = (bx - 3840) * 256 + tid;      // < 210,944
        if (idx < 112640) {
            int m = idx / 10240;
            int rem = idx - m * 10240;
            int n = rem / 160, k = rem - n * 160;
            float v = 0.f;
            if (k < 80) {
                if (k < 75) v = (m == 0) ? 0.f : W1[(size_t)(2*m-2)*75*64 + k*64 + n];
            } else {
                int kk = k - 80;
                if (kk < 75) v = (m == 0) ? W1[(size_t)20*75*64 + kk*64 + n]
                                          : W1[(size_t)(2*m-1)*75*64 + kk*64 + n];
            }
            Wt1[(size_t)m*10240 + n*160 + k] = f2bf(v);
        } else if (idx < 202752) {
            int i2 = idx - 112640;
            int m = i2 / 8192;
            int rem = i2 - m * 8192;
            int n = rem / 128, k = rem - n * 128;
            float v;
            if (k < 64) v = (m == 0) ? 0.f : W2[(size_t)(2*m-2)*64*64 + k*64 + n];
            else        v = (m == 0) ? W2[(size_t)20*64*64 + (k-64)*64 + n]
                                     : W2[(size_t)(2*m-1)*64*64 + (k-64)*64 + n];
            Wt2[(size_t)m*8192 + n*128 + k] = f2bf(v);
        } else {
            int i3 = idx - 202752;                  // 8192: Wt3[n][k] = W3[k][n]
            int n = i3 >> 6, k = i3 & 63;
            Wt3[(size_t)n*64 + k] = f2bf(W3[(size_t)k*128 + n]);
        }
    } else {
        hist[(bx - 4664) * 256 + tid] = 0;
    }
}

__global__ __launch_bounds__(256)
void hist_kernel(const int* __restrict__ mem, int* __restrict__ hist) {
    int i = blockIdx.x * 256 + threadIdx.x;    // grid 480
    atomicAdd(&hist[mem[i]], 1);
}

__global__ __launch_bounds__(1024)
void scan_kernel(const int* __restrict__ hist, int* __restrict__ cursor) {
    __shared__ int s_sums[16];
    const int t = threadIdx.x;
    const int lane = t & 63, wid = t >> 6;
    int4 v = ((const int4*)hist)[t];
    int tot = v.x + v.y + v.z + v.w;
    int x = tot;
    #pragma unroll
    for (int o = 1; o < 64; o <<= 1) { int y = __shfl_up(x, o); if (lane >= o) x += y; }
    if (lane == 63) s_sums[wid] = x;
    __syncthreads();
    if (wid == 0) {
        int y = (lane < 16) ? s_sums[lane] : 0;
        #pragma unroll
        for (int o = 1; o < 16; o <<= 1) { int z = __shfl_up(y, o); if (lane >= o) y += z; }
        if (lane < 16) s_sums[lane] = y;
    }
    __syncthreads();
    int base = (wid > 0 ? s_sums[wid - 1] : 0) + (x - tot);
    int4 c;
    c.x = base; c.y = base + v.x; c.z = base + v.x + v.y; c.w = base + v.x + v.y + v.z;
    ((int4*)cursor)[t] = c;
}

__global__ __launch_bounds__(256)
void scatter_kernel(const int* __restrict__ mem, int* __restrict__ cursor,
                    int* __restrict__ sidx) {
    int i = blockIdx.x * 256 + threadIdx.x;    // grid 480
    int m = mem[i];
    int p = atomicAdd(&cursor[m], 1);
    sidx[p] = i;
}

// ---------------- conv (MFMA) ----------------

// Staging v2: threads cover (atom, 16B-chunk); per thread d+1 independent uint4 loads.
template<int FP, int KPAD, int D>
__device__ inline void stage_rows_v2(ushort (*s_A)[KPAD], const int* __restrict__ s_adj,
                                     const ushort* __restrict__ xb, int row0, int tid)
{
    constexpr int NCH = FP / 8;
    for (int e = tid; e < 32 * NCH; e += 256) {
        const int a = e / NCH, ch = e - a * NCH;
        const int co = ch * 8;
        uint4 sv = *(const uint4*)(xb + (size_t)(row0 + a) * FP + co);
        float acc[8] = {0.f,0.f,0.f,0.f,0.f,0.f,0.f,0.f};
        #pragma unroll
        for (int j = 0; j < D; ++j) {
            uint4 nv = *(const uint4*)(xb + (size_t)s_adj[a * D + j] * FP + co);
            unsigned u[4] = {nv.x, nv.y, nv.z, nv.w};
            #pragma unroll
            for (int q = 0; q < 4; ++q) {
                acc[2*q]   += __uint_as_float(u[q] << 16);
                acc[2*q+1] += __uint_as_float(u[q] & 0xFFFF0000u);
            }
        }
        unsigned pz[4];
        #pragma unroll
        for (int q = 0; q < 4; ++q)
            pz[q] = (unsigned)f2bf(acc[2*q]) | ((unsigned)f2bf(acc[2*q+1]) << 16);
        uint4 rv; rv.x = pz[0]; rv.y = pz[1]; rv.z = pz[2]; rv.w = pz[3];
        *(uint4*)&s_A[a][co] = rv;
        *(uint4*)&s_A[a][FP + co] = sv;
    }
}

// One 32-atom tile. A = [relsum | self] (K=2*FP), B = Wt[d] (64 x KTOT).
template<int FP, int KTOT, int KPAD>
__global__ __launch_bounds__(256)
void conv_mfma(const ushort* __restrict__ xb, const ushort* __restrict__ Wt,
               const float* __restrict__ b,
               const float* __restrict__ g, const float* __restrict__ beta,
               const float* __restrict__ mean, const float* __restrict__ var,
               Adj adj, ushort* __restrict__ out)
{
    __shared__ ushort s_A[32][KPAD];
    __shared__ int s_adj[320];

    const int tid = threadIdx.x;
    const int bx  = blockIdx.x;
    int d = 0;
    #pragma unroll
    for (int i = 1; i <= 10; ++i) if (bx >= d_TCUM[i]) d = i;
    const int tile = bx - d_TCUM[d];
    const int row0 = d_OFFS[d] + tile * 32;

    if (d > 0) {
        const int* ap = adj.p[d-1] + (size_t)tile * 32 * d;
        for (int e = tid; e < 32 * d; e += 256) s_adj[e] = ap[e];
    }
    __syncthreads();

    switch (d) {
        case 0:  stage_rows_v2<FP,KPAD,0 >(s_A, s_adj, xb, row0, tid); break;
        case 1:  stage_rows_v2<FP,KPAD,1 >(s_A, s_adj, xb, row0, tid); break;
        case 2:  stage_rows_v2<FP,KPAD,2 >(s_A, s_adj, xb, row0, tid); break;
        case 3:  stage_rows_v2<FP,KPAD,3 >(s_A, s_adj, xb, row0, tid); break;
        case 4:  stage_rows_v2<FP,KPAD,4 >(s_A, s_adj, xb, row0, tid); break;
        case 5:  stage_rows_v2<FP,KPAD,5 >(s_A, s_adj, xb, row0, tid); break;
        case 6:  stage_rows_v2<FP,KPAD,6 >(s_A, s_adj, xb, row0, tid); break;
        case 7:  stage_rows_v2<FP,KPAD,7 >(s_A, s_adj, xb, row0, tid); break;
        case 8:  stage_rows_v2<FP,KPAD,8 >(s_A, s_adj, xb, row0, tid); break;
        case 9:  stage_rows_v2<FP,KPAD,9 >(s_A, s_adj, xb, row0, tid); break;
        default: stage_rows_v2<FP,KPAD,10>(s_A, s_adj, xb, row0, tid); break;
    }
    __syncthreads();

    // wave w: row-tile r = w&1 (16 atoms), col pair c = w>>1 (2x16 cols)
    const int w = tid >> 6, lane = tid & 63;
    const int r = w & 1, c = w >> 1;
    const int l15 = lane & 15, lg = lane >> 4;
    const int kgrp = lg * 8;

    f32x4 acc0 = {}, acc1 = {};
    const ushort* ap0 = &s_A[r * 16 + l15][kgrp];
    const ushort* wt0 = Wt + ((size_t)d * 64 + c * 32 + l15) * KTOT + kgrp;
    const ushort* wt1 = wt0 + 16 * KTOT;
    #pragma unroll
    for (int ks = 0; ks < KTOT / 32; ++ks) {
        bf16x8 af = *(const bf16x8*)(ap0 + ks * 32);
        bf16x8 b0 = *(const bf16x8*)(wt0 + ks * 32);
        bf16x8 b1 = *(const bf16x8*)(wt1 + ks * 32);
        acc0 = __builtin_amdgcn_mfma_f32_16x16x32_bf16(af, b0, acc0, 0, 0, 0);
        acc1 = __builtin_amdgcn_mfma_f32_16x16x32_bf16(af, b1, acc1, 0, 0, 0);
    }

    const int col0 = c * 32 + l15;
    const int col1 = col0 + 16;
    float bias0, bias1;
    if (d > 0) {
        bias0 = b[(2*d-2)*64 + col0] + b[(2*d-1)*64 + col0];
        bias1 = b[(2*d-2)*64 + col1] + b[(2*d-1)*64 + col1];
    } else {
        bias0 = b[20*64 + col0];
        bias1 = b[20*64 + col1];
    }
    const float g0 = g[col0], be0 = beta[col0], m0 = mean[col0], r0 = rsqrtf(var[col0] + EPS);
    const float g1 = g[col1], be1 = beta[col1], m1 = mean[col1], r1 = rsqrtf(var[col1] + EPS);
    const int rbase = row0 + r * 16 + lg * 4;
    #pragma unroll
    for (int i = 0; i < 4; ++i) {
        float t0 = fast_tanh(acc0[i] + bias0);
        float t1 = fast_tanh(acc1[i] + bias1);
        out[(size_t)(rbase + i) * 64 + col0] = f2bf(g0 * (t0 - m0) * r0 + be0);
        out[(size_t)(rbase + i) * 64 + col1] = f2bf(g1 * (t1 - m1) * r1 + be1);
    }
}

// ---------------- pool (bf16, vectorized 16B/lane) ----------------

template<int D>
__device__ inline void pool_body(const ushort* __restrict__ h, ushort* __restrict__ out,
                                 const int* __restrict__ s_adj, int row0, int tid)
{
    const int a = tid >> 3, co = (tid & 7) * 8;   // 32 atoms x 8 chunks
    uint4 sv = *(const uint4*)(h + (size_t)(row0 + a) * 64 + co);
    unsigned su[4] = {sv.x, sv.y, sv.z, sv.w};
    float mx[8];
    #pragma unroll
    for (int q = 0; q < 4; ++q) {
        mx[2*q]   = __uint_as_float(su[q] << 16);
        mx[2*q+1] = __uint_as_float(su[q] & 0xFFFF0000u);
    }
    #pragma unroll
    for (int j = 0; j < D; ++j) {
        uint4 nv = *(const uint4*)(h + (size_t)s_adj[a * D + j] * 64 + co);
        unsigned u[4] = {nv.x, nv.y, nv.z, nv.w};
        #pragma unroll
        for (int q = 0; q < 4; ++q) {
            mx[2*q]   = fmaxf(mx[2*q],   __uint_as_float(u[q] << 16));
            mx[2*q+1] = fmaxf(mx[2*q+1], __uint_as_float(u[q] & 0xFFFF0000u));
        }
    }
    unsigned pz[4];
    #pragma unroll
    for (int q = 0; q < 4; ++q)   // exact: all values are bf16-representable
        pz[q] = (__float_as_uint(mx[2*q]) >> 16) | (__float_as_uint(mx[2*q+1]) & 0xFFFF0000u);
    uint4 pv; pv.x = pz[0]; pv.y = pz[1]; pv.z = pz[2]; pv.w = pz[3];
    *(uint4*)(out + (size_t)(row0 + a) * 64 + co) = pv;
}

__global__ __launch_bounds__(256)
void pool_tile(const ushort* __restrict__ h, ushort* __restrict__ out, Adj adj)
{
    __shared__ int s_adj[320];
    const int tid = threadIdx.x;
    const int bx  = blockIdx.x;
    int d = 0;
    #pragma unroll
    for (int i = 1; i <= 10; ++i) if (bx >= d_TCUM[i]) d = i;
    const int tile = bx - d_TCUM[d];
    const int row0 = d_OFFS[d] + tile * 32;

    if (d > 0) {
        const int* ap = adj.p[d-1] + (size_t)tile * 32 * d;
        for (int e = tid; e < 32 * d; e += 256) s_adj[e] = ap[e];
        __syncthreads();
    }
    switch (d) {
        case 0:  pool_body<0 >(h, out, s_adj, row0, tid); break;
        case 1:  pool_body<1 >(h, out, s_adj, row0, tid); break;
        case 2:  pool_body<2 >(h, out, s_adj, row0, tid); break;
        case 3:  pool_body<3 >(h, out, s_adj, row0, tid); break;
        case 4:  pool_body<4 >(h, out, s_adj, row0, tid); break;
        case 5:  pool_body<5 >(h, out, s_adj, row0, tid); break;
        case 6:  pool_body<6 >(h, out, s_adj, row0, tid); break;
        case 7:  pool_body<7 >(h, out, s_adj, row0, tid); break;
        case 8:  pool_body<8 >(h, out, s_adj, row0, tid); break;
        case 9:  pool_body<9 >(h, out, s_adj, row0, tid); break;
        default: pool_body<10>(h, out, s_adj, row0, tid); break;
    }
}

// ------- dense d1 (MFMA) + per-molecule reduce + FUSED final (d2/d3) -------
// One block per molecule; writes out[mol] directly. No atomics, no seg arrays.
__global__ __launch_bounds__(256)
void dense_seg_fused(const ushort* __restrict__ h, const ushort* __restrict__ Wt3,
                     const float* __restrict__ b,
                     const float* __restrict__ g3, const float* __restrict__ b3,
                     const float* __restrict__ m3, const float* __restrict__ v3,
                     const int* __restrict__ sidx,
                     const int* __restrict__ hist, const int* __restrict__ endc,
                     const float* __restrict__ x_add,
                     const float* __restrict__ d2W, const float* __restrict__ d2b,
                     const float* __restrict__ d3W, const float* __restrict__ d3b,
                     float* __restrict__ out)
{
    __shared__ ushort s_x[32][72];   // 72-pad: 2-way bank alias (free)
    __shared__ float s_sum[4][64];
    __shared__ float s_max[4][64];
    __shared__ float s_red[4];

    const int mol = blockIdx.x;
    const int cnt = hist[mol];
    const int start = endc[mol] - cnt;

    const int tid = threadIdx.x;
    const int w = tid >> 6, lane = tid & 63;
    const int r = w & 1, cb = (w >> 1) * 64;
    const int l15 = lane & 15, lg = lane >> 4;

    int   col[4];
    float bias[4], gg[4], bb[4], mm[4], rr[4];
    #pragma unroll
    for (int j = 0; j < 4; ++j) {
        col[j]  = cb + j * 16 + l15;
        bias[j] = b[col[j]];
        gg[j] = g3[col[j]]; bb[j] = b3[col[j]]; mm[j] = m3[col[j]];
        rr[j] = rsqrtf(v3[col[j]] + EPS);
    }

    const float NEGINF = __int_as_float(0xFF800000);
    float rsum[4] = {0.f, 0.f, 0.f, 0.f};
    float rmax[4] = {NEGINF, NEGINF, NEGINF, NEGINF};

    const int a = tid >> 3, part = tid & 7;     // staging: 8 threads x 16B per row
    for (int base = 0; base < cnt; base += 32) {
        uint4 val = {0u, 0u, 0u, 0u};
        int ri = base + a;
        if (ri < cnt) {
            int row = sidx[start + ri];
            val = *(const uint4*)(h + (size_t)row * 64 + part * 8);
        }
        *(uint4*)&s_x[a][part * 8] = val;
        __syncthreads();

        f32x4 acc[4] = {};
        const ushort* ap0 = &s_x[r * 16 + l15][lg * 8];
        #pragma unroll
        for (int ks = 0; ks < 2; ++ks) {
            bf16x8 af = *(const bf16x8*)(ap0 + ks * 32);
            #pragma unroll
            for (int j = 0; j < 4; ++j) {
                const ushort* wt = Wt3 + (size_t)col[j] * 64 + lg * 8 + ks * 32;
                bf16x8 bv = *(const bf16x8*)wt;
                acc[j] = __builtin_amdgcn_mfma_f32_16x16x32_bf16(af, bv, acc[j], 0, 0, 0);
            }
        }

        const int rowbase = base + r * 16 + lg * 4;
        #pragma unroll
        for (int i = 0; i < 4; ++i) {
            if (rowbase + i < cnt) {
                #pragma unroll
                for (int j = 0; j < 4; ++j) {
                    float hv = gg[j] * (fast_tanh(acc[j][i] + bias[j]) - mm[j]) * rr[j] + bb[j];
                    rsum[j] += hv;
                    rmax[j] = fmaxf(rmax[j], hv);
                }
            }
        }
        __syncthreads();
    }

    // reduce across the 4 lane-groups (lanes l15, l15+16, l15+32, l15+48 share a col)
    #pragma unroll
    for (int j = 0; j < 4; ++j) {
        rsum[j] += __shfl_xor(rsum[j], 16);
        rsum[j] += __shfl_xor(rsum[j], 32);
        rmax[j] = fmaxf(rmax[j], __shfl_xor(rmax[j], 16));
        rmax[j] = fmaxf(rmax[j], __shfl_xor(rmax[j], 32));
    }
    if (lane < 16) {
        #pragma unroll
        for (int j = 0; j < 4; ++j) {
            s_sum[w][j * 16 + lane] = rsum[j];
            s_max[w][j * 16 + lane] = rmax[j];
        }
    }
    __syncthreads();

    // fused final: p = tanh(mol_vec) . d2W over 256 entries ([sum(128) | max(128)])
    {
        const int part2 = tid >> 7;          // 0 = sum half, 1 = max half
        const int c  = tid & 127;
        const int ch = c >> 6, cc = c & 63;
        float val;
        if (part2 == 0) val = s_sum[2*ch][cc] + s_sum[2*ch + 1][cc];
        else            val = fmaxf(s_max[2*ch][cc], s_max[2*ch + 1][cc]);
        float p = fast_tanh(val) * d2W[part2 * 128 + c];
        #pragma unroll
        for (int o = 32; o > 0; o >>= 1) p += __shfl_down(p, o);
        if (lane == 0) s_red[w] = p;
    }
    __syncthreads();
    if (tid == 0) {
        float mv = s_red[0] + s_red[1] + s_red[2] + s_red[3] + d2b[0];
        float rv = mv * d3W[0] + d3b[0];
        for (int i = 0; i < 15; ++i) rv += x_add[(size_t)mol * 15 + i] * d3W[1 + i];
        out[mol] = rv;
    }
}

extern "C" void kernel_launch(void* const* d_in, const int* in_sizes, int n_in,
                              void* d_out, int out_size, void* d_ws, size_t ws_size,
                              hipStream_t stream) {
    const float* atoms      = (const float*)d_in[0];
    const int*   membership = (const int*)  d_in[1];
    Adj adj;
    for (int i = 0; i < 10; ++i) adj.p[i] = (const int*)d_in[2 + i];
    const float* x_add = (const float*)d_in[12];
    const float* gc1_W = (const float*)d_in[13];
    const float* gc1_b = (const float*)d_in[14];
    const float* gc2_W = (const float*)d_in[15];
    const float* gc2_b = (const float*)d_in[16];
    const float* bn1_g = (const float*)d_in[17];
    const float* bn1_b = (const float*)d_in[18];
    const float* bn1_m = (const float*)d_in[19];
    const float* bn1_v = (const float*)d_in[20];
    const float* bn3_g = (const float*)d_in[21];
    const float* bn3_b = (const float*)d_in[22];
    const float* bn3_m = (const float*)d_in[23];
    const float* bn3_v = (const float*)d_in[24];
    const float* d1_W  = (const float*)d_in[25];
    const float* d1_b  = (const float*)d_in[26];
    const float* d2_W  = (const float*)d_in[27];
    const float* d2_b  = (const float*)d_in[28];
    const float* d3_W  = (const float*)d_in[29];
    const float* d3_b  = (const float*)d_in[30];
    float* out = (float*)d_out;

    // ---- workspace layout (elements) ----
    ushort* xb  = (ushort*)d_ws;                       // 122880*80 = 9,830,400
    ushort* hA  = xb  + (size_t)9830400;               // 7,864,320
    ushort* hB  = hA  + (size_t)7864320;               // 7,864,320
    ushort* Wt1 = hB  + (size_t)7864320;               // 112,640
    ushort* Wt2 = Wt1 + (size_t)112640;                // 90,112
    ushort* Wt3 = Wt2 + (size_t)90112;                 // 8,192
    int*   sidx = (int*)(Wt3 + (size_t)8192);          // NATOMS
    int*   hist = sidx + NATOMS;                       // 4096
    int* cursor = hist + BATCH;                        // 4096

    // pre-pass (cvt | build_wt | zero_hist merged)
    prep_kernel<<<4680, 256, 0, stream>>>(atoms, xb, gc1_W, gc2_W, d1_W,
                                          Wt1, Wt2, Wt3, hist);
    hist_kernel<<<480, 256, 0, stream>>>(membership, hist);
    scan_kernel<<<1, 1024, 0, stream>>>(hist, cursor);
    scatter_kernel<<<480, 256, 0, stream>>>(membership, cursor, sidx);
    // after scatter, cursor[m] == end offset of molecule m

    // main pipeline
    conv_mfma<80,160,168><<<3840, 256, 0, stream>>>(xb, Wt1, gc1_b,
                                                    bn1_g, bn1_b, bn1_m, bn1_v, adj, hA);
    pool_tile<<<3840, 256, 0, stream>>>(hA, hB, adj);
    conv_mfma<64,128,136><<<3840, 256, 0, stream>>>(hB, Wt2, gc2_b,
                                                    bn1_g, bn1_b, bn1_m, bn1_v, adj, hA);
    pool_tile<<<3840, 256, 0, stream>>>(hA, hB, adj);
    dense_seg_fused<<<BATCH, 256, 0, stream>>>(hB, Wt3, d1_b,
                                               bn3_g, bn3_b, bn3_m, bn3_v,
                                               sidx, hist, cursor,
                                               x_add, d2_W, d2_b, d3_W, d3_b, out);
}